// Round 2
// baseline (623.428 us; speedup 1.0000x reference)
//
#include <hip/hip_runtime.h>

// 2x nearest-neighbor upsample: x[16,128,128,128] f32 -> out[16,128,256,256].
//
// R2 change vs R1 (593 µs): batch-8 MLP restructure. R0/R1 showed store
// cache-mode is a null variable. New theory: the one-shot structure
// (1 load -> vmcnt(0) -> 2 stores -> block exit, 65536 blocks) is
// latency-bound on the read side (~900 cy HBM latency, input not
// L3-resident since the 2 GiB re-poison fill flushes L3). Fix: each
// thread issues 8 independent nt loads (strided grid-constant apart,
// each load instruction still 512 B contiguous per wave), then 16
// stores with progressive vmcnt. 8x read MLP, 8x fewer blocks.
//
// Mapping per virtual index (unchanged, proven correct): thread handles
// input float2 `t`; writes (a,a,b,b) float4 to output rows 2h, 2h+1.

typedef float v2f __attribute__((ext_vector_type(2)));
typedef float v4f __attribute__((ext_vector_type(4)));

#define NITER  8
#define BLOCK  256
#define GRID   8192
#define STRIDE (GRID * BLOCK)      // 2,097,152 threads; x8 = 16,777,216 float2s

__global__ __launch_bounds__(BLOCK) void upsample_57312043598151_kernel(
    const v2f* __restrict__ in, v4f* __restrict__ out) {
    const int tid0 = blockIdx.x * BLOCK + threadIdx.x;

    // Phase 1: 8 independent loads in flight (fully unrolled -> registers).
    v2f v[NITER];
#pragma unroll
    for (int i = 0; i < NITER; ++i)
        v[i] = __builtin_nontemporal_load(&in[tid0 + i * STRIDE]);

    // Phase 2: stores (compiler inserts progressive vmcnt(7..0) waits).
#pragma unroll
    for (int i = 0; i < NITER; ++i) {
        const int tid  = tid0 + i * STRIDE;
        const int col2 = tid & 63;   // float2 index within input row (64/row)
        const int r    = tid >> 6;   // flattened (b, c, h) input row
        const int h    = r & 127;
        const int bc   = r >> 7;
        const int out_row0 = bc * 256 + (h << 1);  // H_out = 256

        v4f o;
        o.x = v[i].x; o.y = v[i].x; o.z = v[i].y; o.w = v[i].y;

        const int idx = out_row0 * 64 + col2;  // out row = 64 float4
        out[idx]      = o;  // row 2h
        out[idx + 64] = o;  // row 2h+1
    }
}

extern "C" void kernel_launch(void* const* d_in, const int* in_sizes, int n_in,
                              void* d_out, int out_size, void* d_ws, size_t ws_size,
                              hipStream_t stream) {
    const v2f* in = (const v2f*)d_in[0];
    v4f* out = (v4f*)d_out;

    upsample_57312043598151_kernel<<<GRID, BLOCK, 0, stream>>>(in, out);
}

// Round 3
// 594.379 us; speedup vs baseline: 1.0489x; 1.0489x over previous
//
#include <hip/hip_runtime.h>

// === R3: MEASUREMENT PROBE (intentionally slowed; revert to R1 after) ===
//
// 2x NN upsample, R1 body executed 4x per thread with asm memory barriers
// so rocprof must show the kernel in the top-5 dispatch table (fills are
// ~340 us; this kernel will be >400 us). Goal: read the kernel's OWN
// dur_us / FETCH_SIZE / WRITE_SIZE / hbm_gbps to decide between:
//   H_A: single-pass kernel ~253 us @ 2.6 TB/s (headroom exists)
//   H_B: single-pass kernel ~106 us @ stream roofline (remaining dur_us
//        is harness reset overhead)
// Output is written 4x with identical values -> still correct.
// All accesses nt so the 4 passes generate real HBM traffic (no cache
// collapse); WRITE_SIZE vs 4x512MiB also reveals gfx950 nt-store policy.

typedef float v2f __attribute__((ext_vector_type(2)));
typedef float v4f __attribute__((ext_vector_type(4)));

__device__ __forceinline__ void upsample_body(const v2f* __restrict__ in,
                                              v4f* __restrict__ out,
                                              const int tid) {
    const v2f v = __builtin_nontemporal_load(&in[tid]);

    const int col2 = tid & 63;   // float2 index within input row (W=128 -> 64)
    const int r    = tid >> 6;   // flattened (b, c, h) input row index
    const int h    = r & 127;    // input H coordinate
    const int bc   = r >> 7;     // flattened (b, c)

    const int out_row0 = bc * 256 + (h << 1);  // output row (H_out = 256)

    v4f o;
    o.x = v.x; o.y = v.x; o.z = v.y; o.w = v.y;

    const int idx = out_row0 * 64 + col2;  // float4 index (out row = 64 float4)
    __builtin_nontemporal_store(o, &out[idx]);       // row 2h
    __builtin_nontemporal_store(o, &out[idx + 64]);  // row 2h+1
}

__global__ __launch_bounds__(256) void upsample_57312043598151_kernel(
    const v2f* __restrict__ in, v4f* __restrict__ out) {
    const int tid = blockIdx.x * blockDim.x + threadIdx.x;  // [0, 16777216)

    upsample_body(in, out, tid);          // pass 1 (the "real" one)
    asm volatile("" ::: "memory");
    upsample_body(in, out, tid);          // pass 2 \
    asm volatile("" ::: "memory");        //         } timing ballast with
    upsample_body(in, out, tid);          // pass 3 /  identical traffic
    asm volatile("" ::: "memory");
    upsample_body(in, out, tid);          // pass 4
}

extern "C" void kernel_launch(void* const* d_in, const int* in_sizes, int n_in,
                              void* d_out, int out_size, void* d_ws, size_t ws_size,
                              hipStream_t stream) {
    const v2f* in = (const v2f*)d_in[0];
    v4f* out = (v4f*)d_out;

    const int n = in_sizes[0];          // 33,554,432 floats
    const int n_threads = n / 2;        // one thread per float2 = 16,777,216
    const int block = 256;
    const int grid = n_threads / block; // 65,536

    upsample_57312043598151_kernel<<<grid, block, 0, stream>>>(in, out);
}